// Round 6
// baseline (1950.027 us; speedup 1.0000x reference)
//
#include <hip/hip_runtime.h>
#include <hip/hip_bf16.h>
#include <math.h>

#define B 4
#define S 2048
#define H 768
#define V 32000
#define HID 100
#define G4 400   // 4*HID
#define M_TOT (B*S)
#define PD 2     // xproj prefetch depth (steps)

typedef _Float16 half2_t __attribute__((ext_vector_type(2)));
typedef _Float16 half8_t __attribute__((ext_vector_type(8)));

__device__ __forceinline__ float fdot2_(half2_t a, half2_t b, float c) {
#if __has_builtin(__builtin_amdgcn_fdot2)
  return __builtin_amdgcn_fdot2(a, b, c, false);
#else
  return c + (float)a[0] * (float)b[0] + (float)a[1] * (float)b[1];
#endif
}

__device__ __forceinline__ float sigmoidf_(float x) {
  return 1.0f / (1.0f + __expf(-x));
}
__device__ __forceinline__ float tanhf_(float x) {
  float ax = fabsf(x);
  float e = __expf(-2.0f * ax);
  float t = (1.0f - e) / (1.0f + e);
  return copysignf(t, x);
}

// Raw workgroup barrier: orders LDS (lgkmcnt drain) but does NOT drain vmcnt,
// so global prefetch loads stay in flight across steps.
__device__ __forceinline__ void lds_barrier_() {
  asm volatile("s_waitcnt lgkmcnt(0)" ::: "memory");
  __builtin_amdgcn_s_barrier();
  asm volatile("" ::: "memory");
}

// ---------------- Kernel 1: surprisal (online softmax + gather) --------------
__global__ __launch_bounds__(256) void surprisal_kernel(
    const float* __restrict__ logits, const int* __restrict__ ids,
    const float* __restrict__ mask, float* __restrict__ surp) {
  int row = blockIdx.x;
  const float* x = logits + (size_t)row * V;
  int tid = threadIdx.x;
  float m = -INFINITY, s = 0.0f;
  const float4* x4 = (const float4*)x;
  for (int i = tid; i < V / 4; i += 256) {
    float4 v = x4[i];
    float mv = fmaxf(fmaxf(v.x, v.y), fmaxf(v.z, v.w));
    if (mv > m) { s *= __expf(m - mv); m = mv; }
    s += __expf(v.x - m) + __expf(v.y - m) + __expf(v.z - m) + __expf(v.w - m);
  }
  #pragma unroll
  for (int off = 32; off > 0; off >>= 1) {
    float mo = __shfl_xor(m, off);
    float so = __shfl_xor(s, off);
    float mn = fmaxf(m, mo);
    s = s * __expf(m - mn) + so * __expf(mo - mn);
    m = mn;
  }
  __shared__ float sm[4], ss[4];
  int wid = tid >> 6, lane = tid & 63;
  if (lane == 0) { sm[wid] = m; ss[wid] = s; }
  __syncthreads();
  if (tid == 0) {
    float M = sm[0], Ssum = ss[0];
    #pragma unroll
    for (int w = 1; w < 4; ++w) {
      float mo = sm[w], so = ss[w];
      float mn = fmaxf(M, mo);
      Ssum = Ssum * __expf(M - mn) + so * __expf(mo - mn);
      M = mn;
    }
    float xid = x[ids[row]];
    surp[row] = (M + __logf(Ssum) - xid) * 1.4426950408889634f * mask[row];
  }
}

// ---------------- Kernel 2: x_proj = [hs|surp] @ W_ih^T + b_ih + b_hh --------
#define BM 64
#define BN 64
#define BK 32

__global__ __launch_bounds__(256) void xproj_kernel(
    const float* __restrict__ A,     // hidden_states [M,768]
    const float* __restrict__ surp,  // [M]
    const float* __restrict__ W,     // W_ih [400,769]
    const float* __restrict__ b_ih, const float* __restrict__ b_hh,
    float* __restrict__ xproj) {     // [M,400]
  __shared__ float As[BK][BM];
  __shared__ float Bs[BK][BN];
  int tid = threadIdx.x;
  int m0 = blockIdx.x * BM;
  int n0 = blockIdx.y * BN;
  int tx = tid & 15, ty = tid >> 4;
  float acc[4][4] = {};
  for (int k0 = 0; k0 < H; k0 += BK) {
    #pragma unroll
    for (int l = 0; l < 2; ++l) {
      int idx = tid + l * 256;        // 0..511
      int row = idx >> 3;
      int kq = idx & 7;
      float4 v = *(const float4*)&A[(size_t)(m0 + row) * H + k0 + kq * 4];
      As[kq * 4 + 0][row] = v.x;
      As[kq * 4 + 1][row] = v.y;
      As[kq * 4 + 2][row] = v.z;
      As[kq * 4 + 3][row] = v.w;
    }
    #pragma unroll
    for (int l = 0; l < 8; ++l) {
      int idx = tid + l * 256;        // 0..2047
      int n = idx >> 5;
      int kk = idx & 31;
      int gn = n0 + n;
      Bs[kk][n] = (gn < G4) ? W[(size_t)gn * (H + 1) + k0 + kk] : 0.0f;
    }
    __syncthreads();
    #pragma unroll
    for (int k = 0; k < BK; ++k) {
      float4 a = *(const float4*)&As[k][ty * 4];
      float4 bq = *(const float4*)&Bs[k][tx * 4];
      float av[4] = {a.x, a.y, a.z, a.w};
      float bv[4] = {bq.x, bq.y, bq.z, bq.w};
      #pragma unroll
      for (int i = 0; i < 4; ++i)
        #pragma unroll
        for (int j = 0; j < 4; ++j)
          acc[i][j] += av[i] * bv[j];
    }
    __syncthreads();
  }
  #pragma unroll
  for (int i = 0; i < 4; ++i) {
    int gm = m0 + ty * 4 + i;
    float sv = surp[gm];
    #pragma unroll
    for (int j = 0; j < 4; ++j) {
      int gn = n0 + tx * 4 + j;
      if (gn < G4) {
        float val = acc[i][j] + sv * W[(size_t)gn * (H + 1) + H] + b_ih[gn] + b_hh[gn];
        xproj[(size_t)gm * G4 + gn] = val;
      }
    }
  }
}

// ---------------- Kernel 3: LSTM scan + classifier ---------------------------
// FUSED-GATE structure: thread k (k<100) owns ALL FOUR gate rows of unit k
// (i=k, f=100+k, g=200+k, o=300+k) as half2 in registers (~208 VGPRs; 128
// threads @ launch_bounds(128,1) -> 512-VGPR budget, no spill). Per step:
// broadcast-read h from LDS, 208 x v_dot2_f32_f16, activations, private c
// update, write h[k]. NO gates buffer, ONE LDS round-trip and ONE raw barrier
// per step (double-buffered h). xproj prefetched PD=2 steps ahead
// (statically indexed under unroll 2).
#define NH2 52          // 50 half2 + 2 zero-pad -> 13 x b128
__global__ __launch_bounds__(128, 1) void lstm_kernel(
    const float* __restrict__ xproj,  // [B,S,400]
    const float* __restrict__ W_hh,   // [400,100]
    const float* __restrict__ sent,   // [B,3]
    const float* __restrict__ cls_W,  // [3,103]
    const float* __restrict__ cls_b,  // [3]
    float* __restrict__ out) {        // [B,3]
  int b = blockIdx.x;
  int tid = threadIdx.x;
  __shared__ __align__(16) _Float16 hb0[2 * NH2];
  __shared__ __align__(16) _Float16 hb1[2 * NH2];

  bool active = tid < HID;
  int u = active ? tid : (HID - 1);   // clamped unit index (uniform control flow)

  half2_t wi[NH2], wf[NH2], wg[NH2], wo[NH2];
  {
    const float* pi = W_hh + (size_t)u * HID;
    const float* pf = W_hh + (size_t)(HID + u) * HID;
    const float* pg = W_hh + (size_t)(2 * HID + u) * HID;
    const float* po = W_hh + (size_t)(3 * HID + u) * HID;
    #pragma unroll
    for (int j = 0; j < 50; ++j) {
      wi[j] = half2_t{(_Float16)pi[2 * j], (_Float16)pi[2 * j + 1]};
      wf[j] = half2_t{(_Float16)pf[2 * j], (_Float16)pf[2 * j + 1]};
      wg[j] = half2_t{(_Float16)pg[2 * j], (_Float16)pg[2 * j + 1]};
      wo[j] = half2_t{(_Float16)po[2 * j], (_Float16)po[2 * j + 1]};
    }
    #pragma unroll
    for (int j = 50; j < NH2; ++j) {
      wi[j] = half2_t{0, 0}; wf[j] = half2_t{0, 0};
      wg[j] = half2_t{0, 0}; wo[j] = half2_t{0, 0};
    }
  }

  float c_reg = 0.0f;
  if (tid < 2 * NH2) { hb0[tid] = (_Float16)0; hb1[tid] = (_Float16)0; }
  __syncthreads();

  const float* xp = xproj + (size_t)b * S * G4;
  float xi[PD], xf[PD], xg[PD], xo[PD];
  #pragma unroll
  for (int d = 0; d < PD; ++d) {
    const float* p = xp + (size_t)d * G4;
    xi[d] = p[u];
    xf[d] = p[HID + u];
    xg[d] = p[2 * HID + u];
    xo[d] = p[3 * HID + u];
  }

  #pragma unroll 2
  for (int t = 0; t < S; ++t) {
    int slot = t & (PD - 1);                       // static under unroll 2
    // step t consumes h_{t-1}, which step t-1 wrote to ((t-1)&1 ? hb1 : hb0)
    const half8_t* hr = (t & 1) ? (const half8_t*)hb0 : (const half8_t*)hb1;
    _Float16* hw = (t & 1) ? hb1 : hb0;

    float i0 = 0.f, i1 = 0.f, f0 = 0.f, f1 = 0.f;
    float g0 = 0.f, g1 = 0.f, o0 = 0.f, o1 = 0.f;
    #pragma unroll
    for (int j = 0; j < 13; ++j) {
      half8_t hv = hr[j];                          // uniform addr -> broadcast
      half2_t h0 = {hv[0], hv[1]}, h1 = {hv[2], hv[3]};
      half2_t h2 = {hv[4], hv[5]}, h3 = {hv[6], hv[7]};
      i0 = fdot2_(wi[4 * j + 0], h0, i0);
      f0 = fdot2_(wf[4 * j + 0], h0, f0);
      g0 = fdot2_(wg[4 * j + 0], h0, g0);
      o0 = fdot2_(wo[4 * j + 0], h0, o0);
      i1 = fdot2_(wi[4 * j + 1], h1, i1);
      f1 = fdot2_(wf[4 * j + 1], h1, f1);
      g1 = fdot2_(wg[4 * j + 1], h1, g1);
      o1 = fdot2_(wo[4 * j + 1], h1, o1);
      i0 = fdot2_(wi[4 * j + 2], h2, i0);
      f0 = fdot2_(wf[4 * j + 2], h2, f0);
      g0 = fdot2_(wg[4 * j + 2], h2, g0);
      o0 = fdot2_(wo[4 * j + 2], h2, o0);
      i1 = fdot2_(wi[4 * j + 3], h3, i1);
      f1 = fdot2_(wf[4 * j + 3], h3, f1);
      g1 = fdot2_(wg[4 * j + 3], h3, g1);
      o1 = fdot2_(wo[4 * j + 3], h3, o1);
    }
    float ai = i0 + i1 + xi[slot];
    float af = f0 + f1 + xf[slot];
    float ag = g0 + g1 + xg[slot];
    float ao = o0 + o1 + xo[slot];

    // refill ring slot for step t+PD (stays in flight across raw barriers)
    {
      int tp = (t + PD < S) ? (t + PD) : (S - 1);
      const float* p = xp + (size_t)tp * G4;
      xi[slot] = p[u];
      xf[slot] = p[HID + u];
      xg[slot] = p[2 * HID + u];
      xo[slot] = p[3 * HID + u];
    }

    float ig = sigmoidf_(ai);
    float fg = sigmoidf_(af);
    float gg = tanhf_(ag);
    float og = sigmoidf_(ao);
    c_reg = fg * c_reg + ig * gg;
    float h = og * tanhf_(c_reg);
    if (active) hw[tid] = (_Float16)h;

    lds_barrier_();   // h_t visible; next step writes the OTHER buffer
  }

  // S even -> final h (t = S-1, odd) is in hb1
  if (tid < 3) {
    float acc = cls_b[tid];
    const float* cw = cls_W + tid * (HID + 3);
    #pragma unroll
    for (int j = 0; j < HID; ++j) acc += cw[j] * (float)hb1[j];
    #pragma unroll
    for (int k2 = 0; k2 < 3; ++k2) acc += cw[HID + k2] * sent[b * 3 + k2];
    out[b * 3 + tid] = acc;
  }
}

extern "C" void kernel_launch(void* const* d_in, const int* in_sizes, int n_in,
                              void* d_out, int out_size, void* d_ws, size_t ws_size,
                              hipStream_t stream) {
  const int*   input_ids = (const int*)d_in[0];
  const float* mask      = (const float*)d_in[1];
  const float* sent      = (const float*)d_in[2];
  const float* hs        = (const float*)d_in[3];
  const float* logits    = (const float*)d_in[4];
  const float* W_ih      = (const float*)d_in[5];
  const float* W_hh      = (const float*)d_in[6];
  const float* b_ih      = (const float*)d_in[7];
  const float* b_hh      = (const float*)d_in[8];
  const float* cls_W     = (const float*)d_in[9];
  const float* cls_b     = (const float*)d_in[10];
  float* out = (float*)d_out;

  float* surp  = (float*)d_ws;            // M_TOT floats
  float* xproj = surp + M_TOT;            // M_TOT*400 floats

  surprisal_kernel<<<M_TOT, 256, 0, stream>>>(logits, input_ids, mask, surp);
  xproj_kernel<<<dim3(M_TOT / BM, (G4 + BN - 1) / BN), 256, 0, stream>>>(
      hs, surp, W_ih, b_ih, b_hh, xproj);
  lstm_kernel<<<B, 128, 0, stream>>>(xproj, W_hh, sent, cls_W, cls_b, out);
}

// Round 7
// 1515.470 us; speedup vs baseline: 1.2867x; 1.2867x over previous
//
#include <hip/hip_runtime.h>
#include <hip/hip_bf16.h>
#include <math.h>

#define B 4
#define S 2048
#define H 768
#define V 32000
#define HID 100
#define G4 400   // 4*HID
#define M_TOT (B*S)
#define PD 2     // xproj prefetch depth (steps)

typedef _Float16 half2_t __attribute__((ext_vector_type(2)));
typedef _Float16 half8_t __attribute__((ext_vector_type(8)));

__device__ __forceinline__ float fdot2_(half2_t a, half2_t b, float c) {
#if __has_builtin(__builtin_amdgcn_fdot2)
  return __builtin_amdgcn_fdot2(a, b, c, false);
#else
  return c + (float)a[0] * (float)b[0] + (float)a[1] * (float)b[1];
#endif
}

__device__ __forceinline__ float sigmoidf_(float x) {
  return 1.0f / (1.0f + __expf(-x));
}

// Raw workgroup barrier: orders LDS (lgkmcnt drain) but does NOT drain vmcnt,
// so global prefetch loads stay in flight across steps.
__device__ __forceinline__ void lds_barrier_() {
  asm volatile("s_waitcnt lgkmcnt(0)" ::: "memory");
  __builtin_amdgcn_s_barrier();
  asm volatile("" ::: "memory");
}

// ---------------- Kernel 1: surprisal (online softmax + gather) --------------
__global__ __launch_bounds__(256) void surprisal_kernel(
    const float* __restrict__ logits, const int* __restrict__ ids,
    const float* __restrict__ mask, float* __restrict__ surp) {
  int row = blockIdx.x;
  const float* x = logits + (size_t)row * V;
  int tid = threadIdx.x;
  float m = -INFINITY, s = 0.0f;
  const float4* x4 = (const float4*)x;
  for (int i = tid; i < V / 4; i += 256) {
    float4 v = x4[i];
    float mv = fmaxf(fmaxf(v.x, v.y), fmaxf(v.z, v.w));
    if (mv > m) { s *= __expf(m - mv); m = mv; }
    s += __expf(v.x - m) + __expf(v.y - m) + __expf(v.z - m) + __expf(v.w - m);
  }
  #pragma unroll
  for (int off = 32; off > 0; off >>= 1) {
    float mo = __shfl_xor(m, off);
    float so = __shfl_xor(s, off);
    float mn = fmaxf(m, mo);
    s = s * __expf(m - mn) + so * __expf(mo - mn);
    m = mn;
  }
  __shared__ float sm[4], ss[4];
  int wid = tid >> 6, lane = tid & 63;
  if (lane == 0) { sm[wid] = m; ss[wid] = s; }
  __syncthreads();
  if (tid == 0) {
    float M = sm[0], Ssum = ss[0];
    #pragma unroll
    for (int w = 1; w < 4; ++w) {
      float mo = sm[w], so = ss[w];
      float mn = fmaxf(M, mo);
      Ssum = Ssum * __expf(M - mn) + so * __expf(mo - mn);
      M = mn;
    }
    float xid = x[ids[row]];
    surp[row] = (M + __logf(Ssum) - xid) * 1.4426950408889634f * mask[row];
  }
}

// ---------------- Kernel 2: x_proj (PERMUTED: col 4*unit+gate) ---------------
#define BM 64
#define BN 64
#define BK 32

__global__ __launch_bounds__(256) void xproj_kernel(
    const float* __restrict__ A,     // hidden_states [M,768]
    const float* __restrict__ surp,  // [M]
    const float* __restrict__ W,     // W_ih [400,769]
    const float* __restrict__ b_ih, const float* __restrict__ b_hh,
    float* __restrict__ xproj) {     // [M,400] permuted
  __shared__ float As[BK][BM];
  __shared__ float Bs[BK][BN];
  int tid = threadIdx.x;
  int m0 = blockIdx.x * BM;
  int n0 = blockIdx.y * BN;
  int tx = tid & 15, ty = tid >> 4;
  float acc[4][4] = {};
  for (int k0 = 0; k0 < H; k0 += BK) {
    #pragma unroll
    for (int l = 0; l < 2; ++l) {
      int idx = tid + l * 256;        // 0..511
      int row = idx >> 3;
      int kq = idx & 7;
      float4 v = *(const float4*)&A[(size_t)(m0 + row) * H + k0 + kq * 4];
      As[kq * 4 + 0][row] = v.x;
      As[kq * 4 + 1][row] = v.y;
      As[kq * 4 + 2][row] = v.z;
      As[kq * 4 + 3][row] = v.w;
    }
    #pragma unroll
    for (int l = 0; l < 8; ++l) {
      int idx = tid + l * 256;        // 0..2047
      int n = idx >> 5;
      int kk = idx & 31;
      int gn = n0 + n;
      Bs[kk][n] = (gn < G4) ? W[(size_t)gn * (H + 1) + k0 + kk] : 0.0f;
    }
    __syncthreads();
    #pragma unroll
    for (int k = 0; k < BK; ++k) {
      float4 a = *(const float4*)&As[k][ty * 4];
      float4 bq = *(const float4*)&Bs[k][tx * 4];
      float av[4] = {a.x, a.y, a.z, a.w};
      float bv[4] = {bq.x, bq.y, bq.z, bq.w};
      #pragma unroll
      for (int i = 0; i < 4; ++i)
        #pragma unroll
        for (int j = 0; j < 4; ++j)
          acc[i][j] += av[i] * bv[j];
    }
    __syncthreads();
  }
  #pragma unroll
  for (int i = 0; i < 4; ++i) {
    int gm = m0 + ty * 4 + i;
    float sv = surp[gm];
    #pragma unroll
    for (int j = 0; j < 4; ++j) {
      int gn = n0 + tx * 4 + j;   // gate-row index r = g*100 + k
      if (gn < G4) {
        float val = acc[i][j] + sv * W[(size_t)gn * (H + 1) + H] + b_ih[gn] + b_hh[gn];
        int pn = 4 * (gn % HID) + gn / HID;   // permuted col: 4*unit + gate
        xproj[(size_t)gm * G4 + pn] = val;
      }
    }
  }
}

// ---------------- Kernel 3: LSTM scan + classifier ---------------------------
// LANE-QUAD structure: thread p (p<400) owns gate-row (p&3)*100 + (p>>2), so
// quad (4k..4k+3) holds (i,f,g,o) of unit k. Per step: broadcast-read h (13 x
// ds_read_b128), 52 x v_dot2_f32_f16, OWN-gate activation (uniform
// sigma(is_g?2a:a) trick -> 1 exp+1 rcp dense), 3 x shfl_xor to gather the
// quad, c update + tanh(c) in registers, lane 4k writes h[k]. No gates LDS
// buffer; ONE raw barrier per step; double-buffered h. xproj pre-permuted so
// the per-step load xp[t*400+p] is fully coalesced. PD=2 prefetch ring.
#define NH2 52          // 50 half2 + 2 zero-pad -> 13 x b128
__global__ __launch_bounds__(448, 1) void lstm_kernel(
    const float* __restrict__ xproj,  // [B,S,400] permuted cols
    const float* __restrict__ W_hh,   // [400,100]
    const float* __restrict__ sent,   // [B,3]
    const float* __restrict__ cls_W,  // [3,103]
    const float* __restrict__ cls_b,  // [3]
    float* __restrict__ out) {        // [B,3]
  int b = blockIdx.x;
  int tid = threadIdx.x;
  __shared__ __align__(16) _Float16 hb0[2 * NH2];
  __shared__ __align__(16) _Float16 hb1[2 * NH2];

  bool active = tid < G4;
  int p = active ? tid : (G4 - 1);     // clamp for uniform control flow
  int k = p >> 2, g = p & 3;
  int r = g * HID + k;                 // gate-row in W_hh
  bool is_g = (g == 2);

  half2_t w[NH2];
  {
    const float* wr = W_hh + (size_t)r * HID;
    #pragma unroll
    for (int j = 0; j < 50; ++j)
      w[j] = half2_t{(_Float16)wr[2 * j], (_Float16)wr[2 * j + 1]};
    #pragma unroll
    for (int j = 50; j < NH2; ++j) w[j] = half2_t{0, 0};
  }

  float c_reg = 0.0f;
  if (tid < 2 * NH2) { hb0[tid] = (_Float16)0; hb1[tid] = (_Float16)0; }
  __syncthreads();

  const float* xp = xproj + (size_t)b * S * G4;
  float xr[PD];
  #pragma unroll
  for (int d = 0; d < PD; ++d) xr[d] = xp[(size_t)d * G4 + p];

  #pragma unroll 2
  for (int t = 0; t < S; ++t) {
    int slot = t & (PD - 1);                       // static under unroll 2
    const half8_t* hr = (t & 1) ? (const half8_t*)hb0 : (const half8_t*)hb1;
    _Float16* hw = (t & 1) ? hb1 : hb0;

    float a0 = 0.f, a1 = 0.f;
    #pragma unroll
    for (int j = 0; j < 13; ++j) {
      half8_t hv = hr[j];                          // uniform addr -> broadcast
      half2_t h0 = {hv[0], hv[1]}, h1 = {hv[2], hv[3]};
      half2_t h2 = {hv[4], hv[5]}, h3 = {hv[6], hv[7]};
      a0 = fdot2_(w[4 * j + 0], h0, a0);
      a1 = fdot2_(w[4 * j + 1], h1, a1);
      a0 = fdot2_(w[4 * j + 2], h2, a0);
      a1 = fdot2_(w[4 * j + 3], h3, a1);
    }
    float a = a0 + a1 + xr[slot];

    // refill ring slot for step t+PD (stays in flight across raw barriers)
    {
      int tp = (t + PD < S) ? (t + PD) : (S - 1);
      xr[slot] = xp[(size_t)tp * G4 + p];
    }

    // own-gate activation, uniform path: g-gate tanh via 2*sigma(2a)-1
    float xa = is_g ? 2.0f * a : a;
    float sg = sigmoidf_(xa);
    float val = is_g ? (2.0f * sg - 1.0f) : sg;

    // gather quad: on lane 4k: val=i, vf=f, vg=g, vo=o
    float vf = __shfl_xor(val, 1);
    float vg = __shfl_xor(val, 2);
    float vo = __shfl_xor(vf, 2);

    c_reg = vf * c_reg + val * vg;                 // c = f*c + i*g (lane 4k)
    float tc = 2.0f * sigmoidf_(2.0f * c_reg) - 1.0f;  // tanh(c)
    float h = vo * tc;
    if (active && g == 0) hw[k] = (_Float16)h;

    lds_barrier_();   // h_t visible; next step writes the OTHER buffer
  }

  // S even -> final h (t = S-1, odd) is in hb1
  if (tid < 3) {
    float acc = cls_b[tid];
    const float* cw = cls_W + tid * (HID + 3);
    #pragma unroll
    for (int j = 0; j < HID; ++j) acc += cw[j] * (float)hb1[j];
    #pragma unroll
    for (int k2 = 0; k2 < 3; ++k2) acc += cw[HID + k2] * sent[b * 3 + k2];
    out[b * 3 + tid] = acc;
  }
}

extern "C" void kernel_launch(void* const* d_in, const int* in_sizes, int n_in,
                              void* d_out, int out_size, void* d_ws, size_t ws_size,
                              hipStream_t stream) {
  const int*   input_ids = (const int*)d_in[0];
  const float* mask      = (const float*)d_in[1];
  const float* sent      = (const float*)d_in[2];
  const float* hs        = (const float*)d_in[3];
  const float* logits    = (const float*)d_in[4];
  const float* W_ih      = (const float*)d_in[5];
  const float* W_hh      = (const float*)d_in[6];
  const float* b_ih      = (const float*)d_in[7];
  const float* b_hh      = (const float*)d_in[8];
  const float* cls_W     = (const float*)d_in[9];
  const float* cls_b     = (const float*)d_in[10];
  float* out = (float*)d_out;

  float* surp  = (float*)d_ws;            // M_TOT floats
  float* xproj = surp + M_TOT;            // M_TOT*400 floats

  surprisal_kernel<<<M_TOT, 256, 0, stream>>>(logits, input_ids, mask, surp);
  xproj_kernel<<<dim3(M_TOT / BM, (G4 + BN - 1) / BN), 256, 0, stream>>>(
      hs, surp, W_ih, b_ih, b_hh, xproj);
  lstm_kernel<<<B, 448, 0, stream>>>(xproj, W_hh, sent, cls_W, cls_b, out);
}

// Round 8
// 1403.221 us; speedup vs baseline: 1.3897x; 1.0800x over previous
//
#include <hip/hip_runtime.h>
#include <hip/hip_bf16.h>
#include <math.h>

#define B 4
#define S 2048
#define H 768
#define V 32000
#define HID 100
#define G4 400   // 4*HID
#define M_TOT (B*S)
#define PD 2     // xproj prefetch depth (steps)

typedef _Float16 half2_t __attribute__((ext_vector_type(2)));
typedef _Float16 half8_t __attribute__((ext_vector_type(8)));

__device__ __forceinline__ float fdot2_(half2_t a, half2_t b, float c) {
#if __has_builtin(__builtin_amdgcn_fdot2)
  return __builtin_amdgcn_fdot2(a, b, c, false);
#else
  return c + (float)a[0] * (float)b[0] + (float)a[1] * (float)b[1];
#endif
}

__device__ __forceinline__ float sigmoidf_(float x) {
  return 1.0f / (1.0f + __expf(-x));
}

// Raw workgroup barrier: orders LDS (lgkmcnt drain) but does NOT drain vmcnt,
// so global prefetch loads stay in flight across steps.
__device__ __forceinline__ void lds_barrier_() {
  asm volatile("s_waitcnt lgkmcnt(0)" ::: "memory");
  __builtin_amdgcn_s_barrier();
  asm volatile("" ::: "memory");
}

// ---------------- Kernel 1: surprisal (online softmax + gather) --------------
__global__ __launch_bounds__(256) void surprisal_kernel(
    const float* __restrict__ logits, const int* __restrict__ ids,
    const float* __restrict__ mask, float* __restrict__ surp) {
  int row = blockIdx.x;
  const float* x = logits + (size_t)row * V;
  int tid = threadIdx.x;
  float m = -INFINITY, s = 0.0f;
  const float4* x4 = (const float4*)x;
  for (int i = tid; i < V / 4; i += 256) {
    float4 v = x4[i];
    float mv = fmaxf(fmaxf(v.x, v.y), fmaxf(v.z, v.w));
    if (mv > m) { s *= __expf(m - mv); m = mv; }
    s += __expf(v.x - m) + __expf(v.y - m) + __expf(v.z - m) + __expf(v.w - m);
  }
  #pragma unroll
  for (int off = 32; off > 0; off >>= 1) {
    float mo = __shfl_xor(m, off);
    float so = __shfl_xor(s, off);
    float mn = fmaxf(m, mo);
    s = s * __expf(m - mn) + so * __expf(mo - mn);
    m = mn;
  }
  __shared__ float sm[4], ss[4];
  int wid = tid >> 6, lane = tid & 63;
  if (lane == 0) { sm[wid] = m; ss[wid] = s; }
  __syncthreads();
  if (tid == 0) {
    float M = sm[0], Ssum = ss[0];
    #pragma unroll
    for (int w = 1; w < 4; ++w) {
      float mo = sm[w], so = ss[w];
      float mn = fmaxf(M, mo);
      Ssum = Ssum * __expf(M - mn) + so * __expf(mo - mn);
      M = mn;
    }
    float xid = x[ids[row]];
    surp[row] = (M + __logf(Ssum) - xid) * 1.4426950408889634f * mask[row];
  }
}

// ---------------- Kernel 2: x_proj (PERMUTED: col 4*unit + bitrev2(gate)) ----
// gate g in {i=0,f=1,g=2,o=3} -> slot {0,2,1,3}; so thread q of the LSTM
// (even q: unit q/2 gates (i,g); odd q: gates (f,o)) loads one float2 at 2q.
#define BM 64
#define BN 64
#define BK 32

__global__ __launch_bounds__(256) void xproj_kernel(
    const float* __restrict__ A,     // hidden_states [M,768]
    const float* __restrict__ surp,  // [M]
    const float* __restrict__ W,     // W_ih [400,769]
    const float* __restrict__ b_ih, const float* __restrict__ b_hh,
    float* __restrict__ xproj) {     // [M,400] permuted
  __shared__ float As[BK][BM];
  __shared__ float Bs[BK][BN];
  int tid = threadIdx.x;
  int m0 = blockIdx.x * BM;
  int n0 = blockIdx.y * BN;
  int tx = tid & 15, ty = tid >> 4;
  float acc[4][4] = {};
  for (int k0 = 0; k0 < H; k0 += BK) {
    #pragma unroll
    for (int l = 0; l < 2; ++l) {
      int idx = tid + l * 256;        // 0..511
      int row = idx >> 3;
      int kq = idx & 7;
      float4 v = *(const float4*)&A[(size_t)(m0 + row) * H + k0 + kq * 4];
      As[kq * 4 + 0][row] = v.x;
      As[kq * 4 + 1][row] = v.y;
      As[kq * 4 + 2][row] = v.z;
      As[kq * 4 + 3][row] = v.w;
    }
    #pragma unroll
    for (int l = 0; l < 8; ++l) {
      int idx = tid + l * 256;        // 0..2047
      int n = idx >> 5;
      int kk = idx & 31;
      int gn = n0 + n;
      Bs[kk][n] = (gn < G4) ? W[(size_t)gn * (H + 1) + k0 + kk] : 0.0f;
    }
    __syncthreads();
    #pragma unroll
    for (int k = 0; k < BK; ++k) {
      float4 a = *(const float4*)&As[k][ty * 4];
      float4 bq = *(const float4*)&Bs[k][tx * 4];
      float av[4] = {a.x, a.y, a.z, a.w};
      float bv[4] = {bq.x, bq.y, bq.z, bq.w};
      #pragma unroll
      for (int i = 0; i < 4; ++i)
        #pragma unroll
        for (int j = 0; j < 4; ++j)
          acc[i][j] += av[i] * bv[j];
    }
    __syncthreads();
  }
  #pragma unroll
  for (int i = 0; i < 4; ++i) {
    int gm = m0 + ty * 4 + i;
    float sv = surp[gm];
    #pragma unroll
    for (int j = 0; j < 4; ++j) {
      int gn = n0 + tx * 4 + j;   // gate-row index r = g*100 + k
      if (gn < G4) {
        float val = acc[i][j] + sv * W[(size_t)gn * (H + 1) + H] + b_ih[gn] + b_hh[gn];
        int g = gn / HID, k = gn % HID;
        int pn = 4 * k + (((g & 1) << 1) | (g >> 1));   // bitrev2(g)
        xproj[(size_t)gm * G4 + pn] = val;
      }
    }
  }
}

// ---------------- Kernel 3: LSTM scan + classifier ---------------------------
// PAIR structure: thread q (q<200) owns TWO gate rows of unit k=q/2:
//   even q -> (i, g) rows;  odd q -> (f, o) rows.  Weights as half2 in regs.
// Per step: broadcast-read h (13 ds_read_b128), 104 v_dot2_f32_f16 (4 indep
// 26-deep chains), LOCAL activations (even: sigma(i), tanh(g); odd: sigma(f),
// sigma(o)), two INDEPENDENT shfl_xor(1) bring f,o to the even lane, c update
// + tanh(c), even lane writes h[k]. No gates buffer; ONE raw barrier/step;
// double-buffered h; 4 waves (1/SIMD). xproj pre-permuted -> one coalesced
// float2 load per thread per step, PD=2 prefetch ring.
#define NH2 52          // 50 half2 + 2 zero-pad -> 13 x b128
__global__ __launch_bounds__(256, 1) void lstm_kernel(
    const float* __restrict__ xproj,  // [B,S,400] permuted cols
    const float* __restrict__ W_hh,   // [400,100]
    const float* __restrict__ sent,   // [B,3]
    const float* __restrict__ cls_W,  // [3,103]
    const float* __restrict__ cls_b,  // [3]
    float* __restrict__ out) {        // [B,3]
  int b = blockIdx.x;
  int tid = threadIdx.x;
  __shared__ __align__(16) _Float16 hb0[2 * NH2];
  __shared__ __align__(16) _Float16 hb1[2 * NH2];

  bool active = tid < 200;
  int q = active ? tid : 199;          // clamp for uniform control flow
  int k = q >> 1;
  bool odd = (q & 1) != 0;
  int rA = odd ? (HID + k) : k;            // f : i
  int rB = odd ? (3 * HID + k) : (2 * HID + k);  // o : g

  half2_t wA[NH2], wB[NH2];
  {
    const float* pA = W_hh + (size_t)rA * HID;
    const float* pB = W_hh + (size_t)rB * HID;
    #pragma unroll
    for (int j = 0; j < 50; ++j) {
      wA[j] = half2_t{(_Float16)pA[2 * j], (_Float16)pA[2 * j + 1]};
      wB[j] = half2_t{(_Float16)pB[2 * j], (_Float16)pB[2 * j + 1]};
    }
    #pragma unroll
    for (int j = 50; j < NH2; ++j) { wA[j] = half2_t{0, 0}; wB[j] = half2_t{0, 0}; }
  }

  float c_reg = 0.0f;
  if (tid < 2 * NH2) { hb0[tid] = (_Float16)0; hb1[tid] = (_Float16)0; }
  __syncthreads();

  const float* xp = xproj + (size_t)b * S * G4;
  float2 xr[PD];
  #pragma unroll
  for (int d = 0; d < PD; ++d)
    xr[d] = ((const float2*)(xp + (size_t)d * G4))[q];

  #pragma unroll 2
  for (int t = 0; t < S; ++t) {
    int slot = t & (PD - 1);                       // static under unroll 2
    const half8_t* hr = (t & 1) ? (const half8_t*)hb0 : (const half8_t*)hb1;
    _Float16* hw = (t & 1) ? hb1 : hb0;

    float2 xv = xr[slot];
    // refill ring slot early (independent; stays in flight across barriers)
    {
      int tp = (t + PD < S) ? (t + PD) : (S - 1);
      xr[slot] = ((const float2*)(xp + (size_t)tp * G4))[q];
    }

    float a0 = 0.f, a1 = 0.f, b0 = 0.f, b1 = 0.f;
    #pragma unroll
    for (int j = 0; j < 13; ++j) {
      half8_t hv = hr[j];                          // uniform addr -> broadcast
      half2_t h0 = {hv[0], hv[1]}, h1 = {hv[2], hv[3]};
      half2_t h2 = {hv[4], hv[5]}, h3 = {hv[6], hv[7]};
      a0 = fdot2_(wA[4 * j + 0], h0, a0);
      b0 = fdot2_(wB[4 * j + 0], h0, b0);
      a1 = fdot2_(wA[4 * j + 1], h1, a1);
      b1 = fdot2_(wB[4 * j + 1], h1, b1);
      a0 = fdot2_(wA[4 * j + 2], h2, a0);
      b0 = fdot2_(wB[4 * j + 2], h2, b0);
      a1 = fdot2_(wA[4 * j + 3], h3, a1);
      b1 = fdot2_(wB[4 * j + 3], h3, b1);
    }
    float aA = a0 + a1 + xv.x;   // even: i_pre ; odd: f_pre
    float aB = b0 + b1 + xv.y;   // even: g_pre ; odd: o_pre

    // local activations (uniform instruction stream, per-lane selects):
    float vA = sigmoidf_(aA);                       // i or f
    float sB = sigmoidf_(odd ? aB : 2.0f * aB);
    float vB = odd ? sB : (2.0f * sB - 1.0f);       // o or tanh(g)

    // two independent pair-exchanges: even lane receives f and o
    float f_n = __shfl_xor(vA, 1);
    float o_n = __shfl_xor(vB, 1);

    // cell update on even lanes: c = f*c + i*g ; h = o * tanh(c)
    c_reg = f_n * c_reg + vA * vB;
    float tc = 2.0f * sigmoidf_(2.0f * c_reg) - 1.0f;
    float h = o_n * tc;
    if (active && !odd) hw[k] = (_Float16)h;

    lds_barrier_();   // h_t visible; next step writes the OTHER buffer
  }

  // S even -> final h (t = S-1, odd) is in hb1
  if (tid < 3) {
    float acc = cls_b[tid];
    const float* cw = cls_W + tid * (HID + 3);
    #pragma unroll
    for (int j = 0; j < HID; ++j) acc += cw[j] * (float)hb1[j];
    #pragma unroll
    for (int k2 = 0; k2 < 3; ++k2) acc += cw[HID + k2] * sent[b * 3 + k2];
    out[b * 3 + tid] = acc;
  }
}

extern "C" void kernel_launch(void* const* d_in, const int* in_sizes, int n_in,
                              void* d_out, int out_size, void* d_ws, size_t ws_size,
                              hipStream_t stream) {
  const int*   input_ids = (const int*)d_in[0];
  const float* mask      = (const float*)d_in[1];
  const float* sent      = (const float*)d_in[2];
  const float* hs        = (const float*)d_in[3];
  const float* logits    = (const float*)d_in[4];
  const float* W_ih      = (const float*)d_in[5];
  const float* W_hh      = (const float*)d_in[6];
  const float* b_ih      = (const float*)d_in[7];
  const float* b_hh      = (const float*)d_in[8];
  const float* cls_W     = (const float*)d_in[9];
  const float* cls_b     = (const float*)d_in[10];
  float* out = (float*)d_out;

  float* surp  = (float*)d_ws;            // M_TOT floats
  float* xproj = surp + M_TOT;            // M_TOT*400 floats

  surprisal_kernel<<<M_TOT, 256, 0, stream>>>(logits, input_ids, mask, surp);
  xproj_kernel<<<dim3(M_TOT / BM, (G4 + BN - 1) / BN), 256, 0, stream>>>(
      hs, surp, W_ih, b_ih, b_hh, xproj);
  lstm_kernel<<<B, 256, 0, stream>>>(xproj, W_hh, sent, cls_W, cls_b, out);
}